// Round 11
// baseline (7249.067 us; speedup 1.0000x reference)
//
#include <hip/hip_runtime.h>
#include <math.h>

typedef unsigned long long ull;

constexpr int H    = 500;
constexpr int H3   = 1500;
constexpr int SEQ  = 256;
constexpr int V    = 50257;
constexpr int TDEC = 64;
constexpr int NLT  = (V + 255) / 256;  // probs_k blocks (197)
constexpr int SB   = 50;               // scan blocks per direction
constexpr int UPB  = 10;               // hidden units per scan block
constexpr int NDB  = 512;              // decoder blocks (2 per CU, capacity-forced)
constexpr int WKB  = 63;               // worker blocks (A..E, 8 units each)
constexpr int RPW  = 12;               // register-resident rows per non-worker wave
constexpr int NWR  = 8 * RPW;          // 96 reg rows per non-worker block
constexpr int RREG = (NDB - WKB) * NWR;    // 43104 rows held in registers
constexpr int WSR  = (V - RREG + WKB - 1) / WKB;  // 114 streamed rows per worker block

__device__ __forceinline__ float sigmoidf_(float x) { return 1.f / (1.f + expf(-x)); }

__device__ __forceinline__ float wred(float v) {
  #pragma unroll
  for (int off = 32; off > 0; off >>= 1) v += __shfl_down(v, off, 64);
  return v;
}

// LLC-routed (sc1) scalar accesses for cross-block data WITHIN a launch.
__device__ __forceinline__ float gload(const float* p) {
  return __hip_atomic_load((float*)p, __ATOMIC_RELAXED, __HIP_MEMORY_SCOPE_AGENT);
}
__device__ __forceinline__ void gstore(float* p, float v) {
  __hip_atomic_store(p, v, __ATOMIC_RELAXED, __HIP_MEMORY_SCOPE_AGENT);
}
__device__ __forceinline__ ull gload64(const ull* p) {
  return __hip_atomic_load((ull*)p, __ATOMIC_RELAXED, __HIP_MEMORY_SCOPE_AGENT);
}
__device__ __forceinline__ void gstore64(ull* p, ull v) {
  __hip_atomic_store(p, v, __ATOMIC_RELAXED, __HIP_MEMORY_SCOPE_AGENT);
}

// ---------------- tagged-word polls: data arrival IS the sync ----------------
template<int N, int SLP>
__device__ __forceinline__ void poll_tags(const ull* tags, unsigned want,
                                          float* dst, int tid) {
  constexpr int NW = (N + 63) / 64;
  if (tid < 64) {
    ull v[NW];
    bool ok;
    do {
      ok = true;
      #pragma unroll
      for (int j = 0; j < NW; ++j) {
        int k = tid + (j << 6);
        if (k < N) {
          v[j] = gload64(&tags[k]);
          if ((unsigned)(v[j] >> 32) != want) ok = false;
        }
      }
      if (!ok) __builtin_amdgcn_s_sleep(SLP);
    } while (!ok);
    #pragma unroll
    for (int j = 0; j < NW; ++j) {
      int k = tid + (j << 6);
      if (k < N) dst[k] = __uint_as_float((unsigned)v[j]);
    }
  }
  __syncthreads();
}

// poll two tag arrays (500 + 256) in one combined retry loop
__device__ __forceinline__ void poll2_tags(const ull* tA, float* dA,
                                           const ull* tB, float* dB,
                                           unsigned want, int tid) {
  if (tid < 64) {
    ull va[8], vb[4];
    bool ok;
    do {
      ok = true;
      #pragma unroll
      for (int j = 0; j < 8; ++j) {
        int k = tid + (j << 6);
        if (k < 500) {
          va[j] = gload64(&tA[k]);
          if ((unsigned)(va[j] >> 32) != want) ok = false;
        }
      }
      #pragma unroll
      for (int j = 0; j < 4; ++j) {
        int k = tid + (j << 6);
        vb[j] = gload64(&tB[k]);
        if ((unsigned)(vb[j] >> 32) != want) ok = false;
      }
      if (!ok) __builtin_amdgcn_s_sleep(1);
    } while (!ok);
    #pragma unroll
    for (int j = 0; j < 8; ++j) {
      int k = tid + (j << 6);
      if (k < 500) dA[k] = __uint_as_float((unsigned)va[j]);
    }
    #pragma unroll
    for (int j = 0; j < 4; ++j) {
      int k = tid + (j << 6);
      dB[k] = __uint_as_float((unsigned)vb[j]);
    }
  }
  __syncthreads();
}

// ---------------- init: ttok = {tag 1, SOS} ----------------
__global__ void init_k(ull* ttok) {
  if (threadIdx.x == 0) ttok[0] = (1ull << 32) | 1ull;
}

// ---------------- embedding lookup: ex[t] = emb[seq[t]] ----------------
__global__ void embed_k(const int* __restrict__ seq, const float* __restrict__ emb,
                        float* __restrict__ ex) {
  int t = blockIdx.x;
  int tok = seq[t];
  for (int i = threadIdx.x; i < H; i += blockDim.x)
    ex[(size_t)t * H + i] = emb[(size_t)tok * H + i];
}

// ---------------- C[m][n] = bias[n] + sum_k X[m*K+k] * W[n*K+k] ----------------
__global__ __launch_bounds__(256) void gemm_nt(const float* __restrict__ X,
                                               const float* __restrict__ W,
                                               const float* __restrict__ bias,
                                               float* __restrict__ C,
                                               int M, int N, int K) {
  __shared__ float Xs[64][17];
  __shared__ float Ws[64][17];
  int bm = blockIdx.y * 64, bn = blockIdx.x * 64;
  int tid = threadIdx.x;
  int tx = tid % 16, ty = tid / 16;
  float acc[4][4] = {};
  for (int k0 = 0; k0 < K; k0 += 16) {
    for (int i = tid; i < 64 * 16; i += 256) {
      int m = i / 16, k = i % 16;
      int gm = bm + m, gk = k0 + k, gn = bn + m;
      Xs[m][k] = (gm < M && gk < K) ? X[(size_t)gm * K + gk] : 0.f;
      Ws[m][k] = (gn < N && gk < K) ? W[(size_t)gn * K + gk] : 0.f;
    }
    __syncthreads();
    #pragma unroll
    for (int k = 0; k < 16; ++k) {
      float xv[4], wv[4];
      #pragma unroll
      for (int i = 0; i < 4; ++i) xv[i] = Xs[ty * 4 + i][k];
      #pragma unroll
      for (int j = 0; j < 4; ++j) wv[j] = Ws[tx * 4 + j][k];
      #pragma unroll
      for (int i = 0; i < 4; ++i)
        #pragma unroll
        for (int j = 0; j < 4; ++j) acc[i][j] += xv[i] * wv[j];
    }
    __syncthreads();
  }
  for (int i = 0; i < 4; ++i) {
    int gm = bm + ty * 4 + i;
    if (gm >= M) continue;
    for (int j = 0; j < 4; ++j) {
      int gn = bn + tx * 4 + j;
      if (gn >= N) continue;
      C[(size_t)gm * N + gn] = acc[i][j] + bias[gn];
    }
  }
}

// ---------------- persistent GRU scan, tagged-h sync, Whh in registers ----------------
__global__ __launch_bounds__(512, 1) void gru_scan_tag(
    const float* __restrict__ gxF, const float* __restrict__ gxB,
    const float* __restrict__ WhhF, const float* __restrict__ WhhB,
    const float* __restrict__ bhhF, const float* __restrict__ bhhB,
    ull* __restrict__ tAF, ull* __restrict__ tBF,
    ull* __restrict__ tAB, ull* __restrict__ tBB,
    float* __restrict__ yF, float* __restrict__ yB, int ystride) {
  __shared__ float gates[32];
  __shared__ float h_lds[512];
  int dir = blockIdx.x / SB;
  int bu  = blockIdx.x % SB;
  int u0  = bu * UPB;
  const float* gx  = dir ? gxB : gxF;
  const float* Whh = dir ? WhhB : WhhF;
  const float* bhh = dir ? bhhB : bhhF;
  ull* tagA = dir ? tAB : tAF;
  ull* tagB = dir ? tBB : tBF;
  float* y  = dir ? yB : yF;
  int tid = threadIdx.x, lane = tid & 63, wid = tid >> 6;

  float wreg[4][8];
  #pragma unroll
  for (int rr = 0; rr < 4; ++rr) {
    int r = wid + 8 * rr;
    #pragma unroll
    for (int j = 0; j < 8; ++j) {
      int k = lane + 64 * j;
      wreg[rr][j] = (r < 30 && k < 500)
          ? Whh[(size_t)((r / UPB) * 500 + u0 + (r % UPB)) * 500 + k] : 0.f;
    }
  }
  int u = u0 + tid;
  float br = 0.f, bz = 0.f, bn = 0.f;
  if (tid < UPB) { br = bhh[u]; bz = bhh[500 + u]; bn = bhh[1000 + u]; }
  h_lds[tid] = 0.f;
  __syncthreads();

  for (int t = 0; t < SEQ; ++t) {
    ull* wout = (t & 1) ? tagA : tagB;
    ull* win  = (t & 1) ? tagB : tagA;
    int teff = dir ? (SEQ - 1 - t) : t;

    float gxr = 0.f, gxz = 0.f, gxn = 0.f;
    if (tid < UPB) {
      const float* g = gx + (size_t)teff * H3;
      gxr = g[u]; gxz = g[500 + u]; gxn = g[1000 + u];
    }

    if (t > 0 && wid == 0) {
      ull v[8];
      for (;;) {
        bool ok = true;
        #pragma unroll
        for (int j = 0; j < 8; ++j) {
          int k = lane + 64 * j;
          if (k < 500) {
            v[j] = gload64(&win[k]);
            if ((unsigned)(v[j] >> 32) != (unsigned)t) ok = false;
          }
        }
        if (ok) break;
        __builtin_amdgcn_s_sleep(1);
      }
      #pragma unroll
      for (int j = 0; j < 8; ++j) {
        int k = lane + 64 * j;
        if (k < 500) h_lds[k] = __uint_as_float((unsigned)v[j]);
      }
    }
    __syncthreads();                         // SYNC1: h(t-1) staged

    float hold = (tid < UPB) ? h_lds[u] : 0.f;
    float hreg[8];
    #pragma unroll
    for (int j = 0; j < 8; ++j) {
      int k = lane + 64 * j;
      hreg[j] = (k < 500) ? h_lds[k] : 0.f;
    }
    #pragma unroll
    for (int rr = 0; rr < 4; ++rr) {
      int r = wid + 8 * rr;
      if (r < 30) {
        float acc = 0.f;
        #pragma unroll
        for (int j = 0; j < 8; ++j) acc += wreg[rr][j] * hreg[j];
        acc = wred(acc);
        if (lane == 0) gates[r] = acc;
      }
    }
    __syncthreads();                         // SYNC2: gates ready; hreg reads done
    if (tid < UPB) {
      float rr = sigmoidf_(gxr + gates[tid]           + br);
      float zz = sigmoidf_(gxz + gates[UPB + tid]     + bz);
      float nn = tanhf(    gxn + rr * (gates[2 * UPB + tid] + bn));
      float hp = (1.f - zz) * nn + zz * hold;
      ull pv = ((ull)(unsigned)(t + 1) << 32) | (ull)__float_as_uint(hp);
      gstore64(&wout[u], pv);
      y[(size_t)teff * ystride + u] = hp;
    }
  }
}

// ---------------- seed decoder h tags from encoder layer-0 finals (tag 0) -------------
__global__ void seed_k(const ull* __restrict__ tf, const ull* __restrict__ tb,
                       ull* __restrict__ th0a, ull* __restrict__ th1a) {
  int i = threadIdx.x;
  if (i < 500) {
    th0a[i] = (ull)(unsigned)tf[i];
    th1a[i] = (ull)(unsigned)tb[i];
  }
}

// ---------------- enc_out = y1f + y1b ----------------
__global__ void add_k(const float* __restrict__ a, const float* __restrict__ b,
                      float* __restrict__ c, int n) {
  int i = blockIdx.x * blockDim.x + threadIdx.x;
  if (i < n) c[i] = a[i] + b[i];
}

// ---------------- enc_out (256 x 500) -> enc_outT (500 x 256) ----------------
__global__ __launch_bounds__(256) void transposeE_k(const float* __restrict__ A,
                                                    float* __restrict__ B) {
  __shared__ float t[64][65];
  int c0 = blockIdx.x * 64;   // col (0..500)
  int r0 = blockIdx.y * 64;   // row (0..256)
  int tx = threadIdx.x & 63, ty = threadIdx.x >> 6;
  #pragma unroll
  for (int i = 0; i < 64; i += 4) {
    int r = r0 + ty + i, c = c0 + tx;
    if (r < SEQ && c < 500) t[ty + i][tx] = A[(size_t)r * 500 + c];
  }
  __syncthreads();
  #pragma unroll
  for (int i = 0; i < 64; i += 4) {
    int c = c0 + ty + i, r = r0 + tx;
    if (c < 500 && r < SEQ) B[(size_t)c * SEQ + r] = t[tx][ty + i];
  }
}

// ---------------- per-unit GRU cell; publishes tagged ----------------
__device__ __forceinline__ void cell_unit_tag(int u, int lane,
    const float* xf, const float* hf,
    const float* __restrict__ Wih, const float* __restrict__ Whh,
    const float* __restrict__ bih, const float* __restrict__ bhh,
    ull* htag, unsigned want) {
  float g[6];
  #pragma unroll
  for (int kind = 0; kind < 6; ++kind) {
    const float* row = (kind < 3) ? (Wih + (size_t)(kind * 500 + u) * 500)
                                  : (Whh + (size_t)((kind - 3) * 500 + u) * 500);
    const float* vec = (kind < 3) ? xf : hf;
    float acc = 0.f;
    #pragma unroll
    for (int j = 0; j < 8; ++j) {
      int k = lane + 64 * j;
      if (k < 500) acc += row[k] * vec[k];
    }
    g[kind] = wred(acc);
  }
  if (lane == 0) {
    float r = sigmoidf_(g[0] + bih[u]        + g[3] + bhh[u]);
    float z = sigmoidf_(g[1] + bih[500 + u]  + g[4] + bhh[500 + u]);
    float n = tanhf(    g[2] + bih[1000 + u] + r * (g[5] + bhh[1000 + u]));
    float hv = (1.f - z) * n + z * hf[u];
    gstore64(&htag[u], ((ull)want << 32) | (ull)__float_as_uint(hv));
  }
}

// ---------------- PERSISTENT decoder: register-resident out_W ----------------
// 512 blocks x 512 threads (2/CU). Blocks 63..511 hold 96 rows of out_W in
// VGPRs (12 rows/wave x 8 floats/lane = 96 VGPR) for the whole kernel; their F
// is pure VALU. Blocks 0..62 (workers) do A..E, then STREAM the leftover 7153
// rows (114/block, ~1.8 MB/XCD -> L2-resident after step 0). Merge: tagged
// partials {psix then pmt, waitcnt-ordered}; block 0 polls all 512 in parallel
// (no serialized RMW), merges, publishes stats+ttok.
__global__ __launch_bounds__(512, 4) void dec_persist(
    const float* __restrict__ emb,
    const float* __restrict__ dWih, const float* __restrict__ dWhh,
    const float* __restrict__ dbih, const float* __restrict__ dbhh,
    const float* __restrict__ enc_out, const float* __restrict__ enc_outT,
    const float* __restrict__ cW, const float* __restrict__ cb,
    const float* __restrict__ outW, const float* __restrict__ outb,
    ull* __restrict__ th0a, ull* __restrict__ th0b,
    ull* __restrict__ th1a, ull* __restrict__ th1b,
    ull* __restrict__ tsc, ull* __restrict__ tctx, ull* __restrict__ tcvec,
    ull* __restrict__ ttok, ull* __restrict__ pmt, ull* __restrict__ psix,
    float* __restrict__ lg0, float* __restrict__ lg1,
    float* __restrict__ stats, float* __restrict__ out_tokens,
    float* __restrict__ out_probs) {
  __shared__ float4 v4[250];           // xf[0..500) + hf[500..1000)
  __shared__ float hfull[512];
  __shared__ float red[256], sc[256];
  __shared__ float wm[8], wsum[8]; __shared__ int wix[8];
  __shared__ float mm[512], ms[512]; __shared__ int mi[512];
  __shared__ int sh_tk;
  float* xf = (float*)v4;
  float* hf = xf + 500;
  int tid = threadIdx.x, lane = tid & 63, wid = tid >> 6, blk = blockIdx.x;
  bool worker = blk < WKB;
  int u = blk * 8 + wid;

  // register-resident out_W slab for non-workers: rows base..base+11 (per wave)
  float4 wa[RPW], wb[RPW];
  int regbase = 0;
  if (!worker) {
    regbase = (blk - WKB) * NWR + wid * RPW;
    const float4* w4 = (const float4*)outW;
    #pragma unroll
    for (int rr = 0; rr < RPW; ++rr) {
      size_t ro = (size_t)(regbase + rr) * 125;
      wa[rr] = (lane < 125) ? w4[ro + lane] : make_float4(0.f, 0.f, 0.f, 0.f);
      wb[rr] = (lane + 64 < 125) ? w4[ro + lane + 64] : make_float4(0.f, 0.f, 0.f, 0.f);
    }
  }
  // worker streamed-row range
  int srow0 = RREG + blk * WSR;
  int snr   = V - srow0; if (snr > WSR) snr = WSR; if (snr < 0) snr = 0;

  for (int st = 0; st < TDEC; ++st) {
    unsigned want = (unsigned)(st + 1);
    ull* h0r = (st & 1) ? th0b : th0a;
    ull* h0w = (st & 1) ? th0a : th0b;
    ull* h1r = (st & 1) ? th1b : th1a;
    ull* h1w = (st & 1) ? th1a : th1b;
    float* lg_w = (st & 1) ? lg1 : lg0;
    const float* lg_r = (st & 1) ? lg0 : lg1;

    if (worker) {
      // ---- A: layer-0 cell ----
      if (tid == 0) {
        ull tv;
        for (;;) {
          tv = gload64(ttok);
          if ((unsigned)(tv >> 32) == want) break;
          __builtin_amdgcn_s_sleep(1);
        }
        sh_tk = (int)(unsigned)tv;
      }
      __syncthreads();
      int tk = sh_tk;
      if (tid >= 64) {
        for (int i = tid - 64; i < 500; i += 448) xf[i] = emb[(size_t)tk * 500 + i];
      } else {
        #pragma unroll
        for (int j = 0; j < 8; ++j) {
          int k = tid + (j << 6);
          if (k < 500) hf[k] = __uint_as_float((unsigned)gload64(&h0r[k]));  // gated
        }
      }
      __syncthreads();
      if (u < 500) cell_unit_tag(u, lane, xf, hf, dWih, dWhh, dbih, dbhh, h0w, want);
      __syncthreads();

      // ---- B: layer-1 cell ----
      if (tid >= 64) {
        for (int i = tid - 64; i < 500; i += 448)
          hf[i] = __uint_as_float((unsigned)gload64(&h1r[i]));               // gated
      }
      poll_tags<500, 1>(h0w, want, xf, tid);
      if (u < 500) cell_unit_tag(u, lane, xf, hf,
          dWih + 750000, dWhh + 750000, dbih + 1500, dbhh + 1500, h1w, want);
      __syncthreads();

      // ---- C: attention scores (blocks 0..31, 8 each) ----
      if (blk < 32) {
        poll_tags<500, 1>(h1w, want, hfull, tid);
        int s = blk * 8 + wid;
        const float* row = enc_out + (size_t)s * 500;
        float acc = 0.f;
        #pragma unroll
        for (int j = 0; j < 8; ++j) {
          int k = lane + 64 * j;
          if (k < 500) acc += row[k] * hfull[k];
        }
        acc = wred(acc);
        if (lane == 0) gstore64(&tsc[s], ((ull)want << 32) | (ull)__float_as_uint(acc));
        poll_tags<256, 1>(tsc, want, sc, tid);
      } else {
        poll2_tags(h1w, hfull, tsc, sc, want, tid);
      }

      // ---- D: softmax (local) + ctx (8 cols/block, coalesced via enc_outT) ----
      {
        float myv = (tid < 256) ? sc[tid] : 0.f;
        if (tid < 256) red[tid] = myv;
        __syncthreads();
        for (int s = 128; s > 0; s >>= 1) {
          if (tid < s) red[tid] = fmaxf(red[tid], red[tid + s]);
          __syncthreads();
        }
        float m = red[0]; __syncthreads();
        float e = 0.f;
        if (tid < 256) { e = expf(myv - m); red[tid] = e; }
        __syncthreads();
        for (int s = 128; s > 0; s >>= 1) {
          if (tid < s) red[tid] += red[tid + s];
          __syncthreads();
        }
        float inv = 1.f / red[0]; __syncthreads();
        if (tid < 256) sc[tid] = e * inv;
        __syncthreads();
        int j = blk * 8 + wid;
        if (j < 500) {
          const float* col = enc_outT + (size_t)j * SEQ;
          float acc = 0.f;
          #pragma unroll
          for (int q = 0; q < 4; ++q) {
            int s = lane + 64 * q;
            acc += sc[s] * col[s];
          }
          acc = wred(acc);
          if (lane == 0) gstore64(&tctx[j], ((ull)want << 32) | (ull)__float_as_uint(acc));
        }
      }

      // ---- E: cvec (8 rows/block) ----
      if (tid >= 64) for (int i = tid - 64; i < 500; i += 448) xf[i] = hfull[i];
      poll_tags<500, 1>(tctx, want, hf, tid);
      {
        int i = blk * 8 + wid;
        if (i < 500) {
          const float* row = cW + (size_t)i * 1000;
          float acc = 0.f;
          #pragma unroll
          for (int j = 0; j < 16; ++j) {
            int k = lane + 64 * j;
            if (k < 1000) acc += row[k] * xf[k];
          }
          acc = wred(acc);
          if (lane == 0)
            gstore64(&tcvec[i], ((ull)want << 32) | (ull)__float_as_uint(tanhf(acc + cb[i])));
        }
      }
      __syncthreads();
    } else {
      // ---- non-workers: gate on ttok, then write prev-step probs during A..E ----
      if (tid == 0) {
        while ((unsigned)(gload64(ttok) >> 32) < want) __builtin_amdgcn_s_sleep(2);
      }
      __syncthreads();
      if (st > 0) {
        float mM = gload(&stats[2 * (st - 1)]), iS = gload(&stats[2 * (st - 1) + 1]);
        int base = (blk - WKB) * NWR;
        for (int r = tid; r < NWR; r += 512) {
          int v = base + r;
          out_probs[(size_t)(st - 1) * V + v] = expf(lg_r[v] - mM) * iS;
        }
      }
    }

    // ---- F: logits + per-wave online-softmax partials ----
    if (worker) poll_tags<500, 1>(tcvec, want, xf, tid);
    else        poll_tags<500, 16>(tcvec, want, xf, tid);
    const float4* c4 = v4;
    {
      float m = -1e30f, ssum = 0.f; int ix = V;
      if (!worker) {
        // register-resident rows: pure VALU
        float4 cc0 = (lane < 125) ? c4[lane] : make_float4(0.f, 0.f, 0.f, 0.f);
        float4 cc1 = (lane + 64 < 125) ? c4[lane + 64] : make_float4(0.f, 0.f, 0.f, 0.f);
        #pragma unroll
        for (int rr = 0; rr < RPW; ++rr) {
          float a = 0.f;
          if (lane < 125)
            a += wa[rr].x * cc0.x + wa[rr].y * cc0.y + wa[rr].z * cc0.z + wa[rr].w * cc0.w;
          if (lane + 64 < 125)
            a += wb[rr].x * cc1.x + wb[rr].y * cc1.y + wb[rr].z * cc1.z + wb[rr].w * cc1.w;
          float l = wred(a);
          if (lane == 0) {
            int row = regbase + rr;
            l += outb[row];
            lg_w[row] = l;
            if (l > m) { ssum = ssum * expf(m - l) + 1.f; m = l; ix = row; }
            else       { ssum += expf(l - m); }
          }
        }
      } else {
        // streamed rows (L2-resident after step 0)
        int ls = wid * 15, le = ls + 15;
        if (ls > snr) ls = snr;
        if (le > snr) le = snr;
        int r0 = srow0 + ls, r1 = srow0 + le;
        for (int rb = r0; rb < r1; rb += 8) {
          int nr = r1 - rb; if (nr > 8) nr = 8;
          float4 wv0[8], wv1[8];
          #pragma unroll
          for (int rr = 0; rr < 8; ++rr) {
            wv0[rr] = (lane < 125 && rr < nr)
                ? ((const float4*)(outW + (size_t)(rb + rr) * 500))[lane]
                : make_float4(0.f, 0.f, 0.f, 0.f);
          }
          #pragma unroll
          for (int rr = 0; rr < 8; ++rr) {
            int k4 = lane + 64;
            wv1[rr] = (k4 < 125 && rr < nr)
                ? ((const float4*)(outW + (size_t)(rb + rr) * 500))[k4]
                : make_float4(0.f, 0.f, 0.f, 0.f);
          }
          float a[8];
          #pragma unroll
          for (int rr = 0; rr < 8; ++rr) a[rr] = 0.f;
          if (lane < 125) {
            float4 cc = c4[lane];
            #pragma unroll
            for (int rr = 0; rr < 8; ++rr) {
              if (rr < nr) {
                float4 w4 = wv0[rr];
                a[rr] += w4.x * cc.x + w4.y * cc.y + w4.z * cc.z + w4.w * cc.w;
              }
            }
          }
          if (lane + 64 < 125) {
            float4 cc = c4[lane + 64];
            #pragma unroll
            for (int rr = 0; rr < 8; ++rr) {
              if (rr < nr) {
                float4 w4 = wv1[rr];
                a[rr] += w4.x * cc.x + w4.y * cc.y + w4.z * cc.z + w4.w * cc.w;
              }
            }
          }
          #pragma unroll
          for (int rr = 0; rr < 8; ++rr) {
            if (rr < nr) {
              float l = wred(a[rr]);
              if (lane == 0) {
                l += outb[rb + rr];
                lg_w[rb + rr] = l;
                if (l > m) { ssum = ssum * expf(m - l) + 1.f; m = l; ix = rb + rr; }
                else       { ssum += expf(l - m); }
              }
            }
          }
        }
      }
      if (lane == 0) { wm[wid] = m; wsum[wid] = ssum; wix[wid] = ix; }
    }
    __syncthreads();
    if (tid == 0) {
      float M = wm[0], S = wsum[0]; int I = wix[0];
      for (int w2 = 1; w2 < 8; ++w2) {
        if (wm[w2] > M) { S = S * expf(M - wm[w2]) + wsum[w2]; M = wm[w2]; I = wix[w2]; }
        else            { S += wsum[w2] * expf(wm[w2] - M); }
      }
      // publish {s, ix} first, then tagged {tag, m} (waitcnt-ordered)
      gstore64(&psix[blk], ((ull)__float_as_uint(S) << 32) | (ull)(unsigned)I);
      __builtin_amdgcn_s_waitcnt(0);
      gstore64(&pmt[blk], ((ull)want << 32) | (ull)__float_as_uint(M));
    }
    __syncthreads();

    // ---- block 0: parallel-poll all 512 tagged partials, merge, publish ----
    if (blk == 0) {
      {
        ull tv;
        while ((unsigned)((tv = gload64(&pmt[tid])) >> 32) != want)
          __builtin_amdgcn_s_sleep(2);
        mm[tid] = __uint_as_float((unsigned)tv);
        ull sv = gload64(&psix[tid]);
        ms[tid] = __uint_as_float((unsigned)(sv >> 32));
        mi[tid] = (int)(unsigned)sv;
      }
      __syncthreads();
      for (int s = 256; s > 0; s >>= 1) {
        if (tid < s) {
          float ma = mm[tid], mb = mm[tid + s];
          float sa = ms[tid], sb = ms[tid + s];
          int ia = mi[tid], ib = mi[tid + s];
          if (mb > ma || (mb == ma && ib < ia)) {
            ms[tid] = sa * expf(ma - mb) + sb; mm[tid] = mb; mi[tid] = ib;
          } else {
            ms[tid] = sa + sb * expf(mb - ma);
          }
        }
        __syncthreads();
      }
      if (tid == 0) {
        out_tokens[st] = (float)mi[0];
        gstore(&stats[2 * st], mm[0]);
        gstore(&stats[2 * st + 1], 1.f / ms[0]);
        __builtin_amdgcn_s_waitcnt(0);     // stats at LLC before tok publish
        gstore64(ttok, ((ull)(unsigned)(st + 2) << 32) | (ull)(unsigned)mi[0]);
      }
      __syncthreads();
    }

    // ---- workers: prev-step probs at end of step (their streamed rows) ----
    if (worker && st > 0) {
      float mM = gload(&stats[2 * (st - 1)]), iS = gload(&stats[2 * (st - 1) + 1]);
      for (int r = tid; r < snr; r += 512) {
        int v = srow0 + r;
        out_probs[(size_t)(st - 1) * V + v] = expf(lg_r[v] - mM) * iS;
      }
    }
    __syncthreads();
  }
}

// ---------------- wide probs write for the final step ----------------
__global__ __launch_bounds__(256) void probs_k(const float* __restrict__ logits,
    const float* __restrict__ stats, float* __restrict__ out_probs) {
  int v = blockIdx.x * 256 + threadIdx.x;
  if (v < V) out_probs[v] = expf(logits[v] - stats[0]) * stats[1];
}

extern "C" void kernel_launch(void* const* d_in, const int* in_sizes, int n_in,
                              void* d_out, int out_size, void* d_ws, size_t ws_size,
                              hipStream_t stream) {
  const int*   seq   = (const int*)d_in[0];
  const float* emb   = (const float*)d_in[3];
  const float* e0f_Wih = (const float*)d_in[4];
  const float* e0f_Whh = (const float*)d_in[5];
  const float* e0f_bih = (const float*)d_in[6];
  const float* e0f_bhh = (const float*)d_in[7];
  const float* e0b_Wih = (const float*)d_in[8];
  const float* e0b_Whh = (const float*)d_in[9];
  const float* e0b_bih = (const float*)d_in[10];
  const float* e0b_bhh = (const float*)d_in[11];
  const float* e1f_Wih = (const float*)d_in[12];
  const float* e1f_Whh = (const float*)d_in[13];
  const float* e1f_bih = (const float*)d_in[14];
  const float* e1f_bhh = (const float*)d_in[15];
  const float* e1b_Wih = (const float*)d_in[16];
  const float* e1b_Whh = (const float*)d_in[17];
  const float* e1b_bih = (const float*)d_in[18];
  const float* e1b_bhh = (const float*)d_in[19];
  const float* dWih = (const float*)d_in[20];
  const float* dWhh = (const float*)d_in[21];
  const float* dbih = (const float*)d_in[22];
  const float* dbhh = (const float*)d_in[23];
  const float* cW   = (const float*)d_in[24];
  const float* cb   = (const float*)d_in[25];
  const float* outW = (const float*)d_in[26];
  const float* outb = (const float*)d_in[27];

  float* w = (float*)d_ws;
  float* ex      = w;                      // 128000
  float* x1      = ex + 128000;            // 256000
  float* gxf     = x1 + 256000;            // 384000
  float* gxb     = gxf + 384000;           // 384000
  float* y1f     = gxb + 384000;           // 128000
  float* y1b     = y1f + 128000;           // 128000
  float* enc_out = y1b + 128000;           // 128000
  float* lg0     = enc_out + 128000;       // 50432
  float* lg1     = lg0 + 50432;            // 50432
  float* stats   = lg1 + 50432;            // 192 (2 per step)
  ull*   htag    = (ull*)(stats + 192);    // scan tags: 4096 ull (8B-aligned)
  ull* tL0F_A = htag;        ull* tL0F_B = htag + 512;
  ull* tL0B_A = htag + 1024; ull* tL0B_B = htag + 1536;
  ull* tL1F_A = htag + 2048; ull* tL1F_B = htag + 2560;
  ull* tL1B_A = htag + 3072; ull* tL1B_B = htag + 3584;
  ull*   dtag    = htag + 4096;            // decoder tags: 4416 ull
  ull* th0a  = dtag;        ull* th0b = dtag + 512;
  ull* th1a  = dtag + 1024; ull* th1b = dtag + 1536;
  ull* tsc   = dtag + 2048; ull* tctx = dtag + 2304;
  ull* tcvec = dtag + 2816; ull* ttok = dtag + 3328;
  ull* pmt   = dtag + 3392; ull* psix = dtag + 3904;
  float* enc_outT = (float*)(dtag + 4416); // 128000 floats (500 x 256)

  float* outf = (float*)d_out;

  // zero all tag buffers (d_ws is re-poisoned before every call)
  (void)hipMemsetAsync(htag, 0, (4096 + 4416) * sizeof(ull), stream);

  init_k<<<1, 64, 0, stream>>>(ttok);
  embed_k<<<SEQ, 128, 0, stream>>>(seq, emb, ex);

  // encoder layer 0
  gemm_nt<<<dim3(24, 4), 256, 0, stream>>>(ex, e0f_Wih, e0f_bih, gxf, SEQ, H3, H);
  gemm_nt<<<dim3(24, 4), 256, 0, stream>>>(ex, e0b_Wih, e0b_bih, gxb, SEQ, H3, H);
  gru_scan_tag<<<2 * SB, 512, 0, stream>>>(gxf, gxb, e0f_Whh, e0b_Whh,
      e0f_bhh, e0b_bhh, tL0F_A, tL0F_B, tL0B_A, tL0B_B, x1, x1 + 500, 1000);

  // encoder layer 1
  gemm_nt<<<dim3(24, 4), 256, 0, stream>>>(x1, e1f_Wih, e1f_bih, gxf, SEQ, H3, 2 * H);
  gemm_nt<<<dim3(24, 4), 256, 0, stream>>>(x1, e1b_Wih, e1b_bih, gxb, SEQ, H3, 2 * H);
  gru_scan_tag<<<2 * SB, 512, 0, stream>>>(gxf, gxb, e1f_Whh, e1b_Whh,
      e1f_bhh, e1b_bhh, tL1F_A, tL1F_B, tL1B_A, tL1B_B, y1f, y1b, 500);
  add_k<<<(SEQ * H + 255) / 256, 256, 0, stream>>>(y1f, y1b, enc_out, SEQ * H);
  transposeE_k<<<dim3(8, 4), 256, 0, stream>>>(enc_out, enc_outT);

  // seed decoder h tags (layer-0 final states live in the A buffers)
  seed_k<<<1, 512, 0, stream>>>(tL0F_A, tL0B_A, th0a, th1a);

  // persistent decoder: ONE launch, 512 blocks (2/CU), register-resident out_W
  dec_persist<<<NDB, 512, 0, stream>>>(emb,
      dWih, dWhh, dbih, dbhh, enc_out, enc_outT, cW, cb, outW, outb,
      th0a, th0b, th1a, th1b, tsc, tctx, tcvec, ttok, pmt, psix,
      lg0, lg1, stats, outf, outf + TDEC);

  probs_k<<<NLT, 256, 0, stream>>>(((TDEC - 1) & 1) ? lg1 : lg0,
      stats + 2 * (TDEC - 1), outf + TDEC + (size_t)(TDEC - 1) * V);
}

// Round 12
// 5606.541 us; speedup vs baseline: 1.2930x; 1.2930x over previous
//
#include <hip/hip_runtime.h>
#include <math.h>

typedef unsigned long long ull;

constexpr int H    = 500;
constexpr int H3   = 1500;
constexpr int SEQ  = 256;
constexpr int V    = 50257;
constexpr int TDEC = 64;
constexpr int NLT  = (V + 255) / 256;  // probs_k blocks (197)
constexpr int SB   = 50;               // scan blocks per direction
constexpr int UPB  = 10;               // hidden units per scan block
constexpr int NDB  = 256;              // decoder blocks (1 per CU, LDS-forced)
constexpr int WKB  = 63;               // worker blocks (A..E, 8 units each)
constexpr int RPW  = 12;               // register rows per wave (24 float4 = 96 VGPR)
constexpr int NWR  = 8 * RPW;          // 96 reg rows per block
constexpr int RREG = NDB * NWR;        // 24576 rows in registers
constexpr int WLR  = 72;               // LDS rows per block (144 KB)
constexpr int LDS0 = RREG;             // first LDS row = 24576
constexpr int STR0 = RREG + NDB * WLR; // first streamed row = 43008
constexpr int SPB  = 29;               // streamed rows per block (7249 total, L2-fits)

__device__ __forceinline__ float sigmoidf_(float x) { return 1.f / (1.f + expf(-x)); }

__device__ __forceinline__ float wred(float v) {
  #pragma unroll
  for (int off = 32; off > 0; off >>= 1) v += __shfl_down(v, off, 64);
  return v;
}

// LLC-routed (sc1) scalar accesses for cross-block data WITHIN a launch.
__device__ __forceinline__ float gload(const float* p) {
  return __hip_atomic_load((float*)p, __ATOMIC_RELAXED, __HIP_MEMORY_SCOPE_AGENT);
}
__device__ __forceinline__ void gstore(float* p, float v) {
  __hip_atomic_store(p, v, __ATOMIC_RELAXED, __HIP_MEMORY_SCOPE_AGENT);
}
__device__ __forceinline__ ull gload64(const ull* p) {
  return __hip_atomic_load((ull*)p, __ATOMIC_RELAXED, __HIP_MEMORY_SCOPE_AGENT);
}
__device__ __forceinline__ void gstore64(ull* p, ull v) {
  __hip_atomic_store(p, v, __ATOMIC_RELAXED, __HIP_MEMORY_SCOPE_AGENT);
}

// ---------------- tagged-word polls: data arrival IS the sync ----------------
template<int N, int SLP>
__device__ __forceinline__ void poll_tags(const ull* tags, unsigned want,
                                          float* dst, int tid) {
  constexpr int NW = (N + 63) / 64;
  if (tid < 64) {
    ull v[NW];
    bool ok;
    do {
      ok = true;
      #pragma unroll
      for (int j = 0; j < NW; ++j) {
        int k = tid + (j << 6);
        if (k < N) {
          v[j] = gload64(&tags[k]);
          if ((unsigned)(v[j] >> 32) != want) ok = false;
        }
      }
      if (!ok) __builtin_amdgcn_s_sleep(SLP);
    } while (!ok);
    #pragma unroll
    for (int j = 0; j < NW; ++j) {
      int k = tid + (j << 6);
      if (k < N) dst[k] = __uint_as_float((unsigned)v[j]);
    }
  }
  __syncthreads();
}

// poll two tag arrays (500 + 256) in one combined retry loop
__device__ __forceinline__ void poll2_tags(const ull* tA, float* dA,
                                           const ull* tB, float* dB,
                                           unsigned want, int tid) {
  if (tid < 64) {
    ull va[8], vb[4];
    bool ok;
    do {
      ok = true;
      #pragma unroll
      for (int j = 0; j < 8; ++j) {
        int k = tid + (j << 6);
        if (k < 500) {
          va[j] = gload64(&tA[k]);
          if ((unsigned)(va[j] >> 32) != want) ok = false;
        }
      }
      #pragma unroll
      for (int j = 0; j < 4; ++j) {
        int k = tid + (j << 6);
        vb[j] = gload64(&tB[k]);
        if ((unsigned)(vb[j] >> 32) != want) ok = false;
      }
      if (!ok) __builtin_amdgcn_s_sleep(1);
    } while (!ok);
    #pragma unroll
    for (int j = 0; j < 8; ++j) {
      int k = tid + (j << 6);
      if (k < 500) dA[k] = __uint_as_float((unsigned)va[j]);
    }
    #pragma unroll
    for (int j = 0; j < 4; ++j) {
      int k = tid + (j << 6);
      dB[k] = __uint_as_float((unsigned)vb[j]);
    }
  }
  __syncthreads();
}

// ---------------- init: ttok = {tag 1, SOS} ----------------
__global__ void init_k(ull* ttok) {
  if (threadIdx.x == 0) ttok[0] = (1ull << 32) | 1ull;
}

// ---------------- embedding lookup: ex[t] = emb[seq[t]] ----------------
__global__ void embed_k(const int* __restrict__ seq, const float* __restrict__ emb,
                        float* __restrict__ ex) {
  int t = blockIdx.x;
  int tok = seq[t];
  for (int i = threadIdx.x; i < H; i += blockDim.x)
    ex[(size_t)t * H + i] = emb[(size_t)tok * H + i];
}

// ---------------- C[m][n] = bias[n] + sum_k X[m*K+k] * W[n*K+k] ----------------
__global__ __launch_bounds__(256) void gemm_nt(const float* __restrict__ X,
                                               const float* __restrict__ W,
                                               const float* __restrict__ bias,
                                               float* __restrict__ C,
                                               int M, int N, int K) {
  __shared__ float Xs[64][17];
  __shared__ float Ws[64][17];
  int bm = blockIdx.y * 64, bn = blockIdx.x * 64;
  int tid = threadIdx.x;
  int tx = tid % 16, ty = tid / 16;
  float acc[4][4] = {};
  for (int k0 = 0; k0 < K; k0 += 16) {
    for (int i = tid; i < 64 * 16; i += 256) {
      int m = i / 16, k = i % 16;
      int gm = bm + m, gk = k0 + k, gn = bn + m;
      Xs[m][k] = (gm < M && gk < K) ? X[(size_t)gm * K + gk] : 0.f;
      Ws[m][k] = (gn < N && gk < K) ? W[(size_t)gn * K + gk] : 0.f;
    }
    __syncthreads();
    #pragma unroll
    for (int k = 0; k < 16; ++k) {
      float xv[4], wv[4];
      #pragma unroll
      for (int i = 0; i < 4; ++i) xv[i] = Xs[ty * 4 + i][k];
      #pragma unroll
      for (int j = 0; j < 4; ++j) wv[j] = Ws[tx * 4 + j][k];
      #pragma unroll
      for (int i = 0; i < 4; ++i)
        #pragma unroll
        for (int j = 0; j < 4; ++j) acc[i][j] += xv[i] * wv[j];
    }
    __syncthreads();
  }
  for (int i = 0; i < 4; ++i) {
    int gm = bm + ty * 4 + i;
    if (gm >= M) continue;
    for (int j = 0; j < 4; ++j) {
      int gn = bn + tx * 4 + j;
      if (gn >= N) continue;
      C[(size_t)gm * N + gn] = acc[i][j] + bias[gn];
    }
  }
}

// ---------------- persistent GRU scan, tagged-h sync, Whh in registers ----------------
__global__ __launch_bounds__(512, 1) void gru_scan_tag(
    const float* __restrict__ gxF, const float* __restrict__ gxB,
    const float* __restrict__ WhhF, const float* __restrict__ WhhB,
    const float* __restrict__ bhhF, const float* __restrict__ bhhB,
    ull* __restrict__ tAF, ull* __restrict__ tBF,
    ull* __restrict__ tAB, ull* __restrict__ tBB,
    float* __restrict__ yF, float* __restrict__ yB, int ystride) {
  __shared__ float gates[32];
  __shared__ float h_lds[512];
  int dir = blockIdx.x / SB;
  int bu  = blockIdx.x % SB;
  int u0  = bu * UPB;
  const float* gx  = dir ? gxB : gxF;
  const float* Whh = dir ? WhhB : WhhF;
  const float* bhh = dir ? bhhB : bhhF;
  ull* tagA = dir ? tAB : tAF;
  ull* tagB = dir ? tBB : tBF;
  float* y  = dir ? yB : yF;
  int tid = threadIdx.x, lane = tid & 63, wid = tid >> 6;

  float wreg[4][8];
  #pragma unroll
  for (int rr = 0; rr < 4; ++rr) {
    int r = wid + 8 * rr;
    #pragma unroll
    for (int j = 0; j < 8; ++j) {
      int k = lane + 64 * j;
      wreg[rr][j] = (r < 30 && k < 500)
          ? Whh[(size_t)((r / UPB) * 500 + u0 + (r % UPB)) * 500 + k] : 0.f;
    }
  }
  int u = u0 + tid;
  float br = 0.f, bz = 0.f, bn = 0.f;
  if (tid < UPB) { br = bhh[u]; bz = bhh[500 + u]; bn = bhh[1000 + u]; }
  h_lds[tid] = 0.f;
  __syncthreads();

  for (int t = 0; t < SEQ; ++t) {
    ull* wout = (t & 1) ? tagA : tagB;
    ull* win  = (t & 1) ? tagB : tagA;
    int teff = dir ? (SEQ - 1 - t) : t;

    float gxr = 0.f, gxz = 0.f, gxn = 0.f;
    if (tid < UPB) {
      const float* g = gx + (size_t)teff * H3;
      gxr = g[u]; gxz = g[500 + u]; gxn = g[1000 + u];
    }

    if (t > 0 && wid == 0) {
      ull v[8];
      for (;;) {
        bool ok = true;
        #pragma unroll
        for (int j = 0; j < 8; ++j) {
          int k = lane + 64 * j;
          if (k < 500) {
            v[j] = gload64(&win[k]);
            if ((unsigned)(v[j] >> 32) != (unsigned)t) ok = false;
          }
        }
        if (ok) break;
        __builtin_amdgcn_s_sleep(1);
      }
      #pragma unroll
      for (int j = 0; j < 8; ++j) {
        int k = lane + 64 * j;
        if (k < 500) h_lds[k] = __uint_as_float((unsigned)v[j]);
      }
    }
    __syncthreads();                         // SYNC1: h(t-1) staged

    float hold = (tid < UPB) ? h_lds[u] : 0.f;
    float hreg[8];
    #pragma unroll
    for (int j = 0; j < 8; ++j) {
      int k = lane + 64 * j;
      hreg[j] = (k < 500) ? h_lds[k] : 0.f;
    }
    #pragma unroll
    for (int rr = 0; rr < 4; ++rr) {
      int r = wid + 8 * rr;
      if (r < 30) {
        float acc = 0.f;
        #pragma unroll
        for (int j = 0; j < 8; ++j) acc += wreg[rr][j] * hreg[j];
        acc = wred(acc);
        if (lane == 0) gates[r] = acc;
      }
    }
    __syncthreads();                         // SYNC2: gates ready; hreg reads done
    if (tid < UPB) {
      float rr = sigmoidf_(gxr + gates[tid]           + br);
      float zz = sigmoidf_(gxz + gates[UPB + tid]     + bz);
      float nn = tanhf(    gxn + rr * (gates[2 * UPB + tid] + bn));
      float hp = (1.f - zz) * nn + zz * hold;
      ull pv = ((ull)(unsigned)(t + 1) << 32) | (ull)__float_as_uint(hp);
      gstore64(&wout[u], pv);
      y[(size_t)teff * ystride + u] = hp;
    }
  }
}

// ---------------- seed decoder h tags from encoder layer-0 finals (tag 0) -------------
__global__ void seed_k(const ull* __restrict__ tf, const ull* __restrict__ tb,
                       ull* __restrict__ th0a, ull* __restrict__ th1a) {
  int i = threadIdx.x;
  if (i < 500) {
    th0a[i] = (ull)(unsigned)tf[i];
    th1a[i] = (ull)(unsigned)tb[i];
  }
}

// ---------------- enc_out = y1f + y1b ----------------
__global__ void add_k(const float* __restrict__ a, const float* __restrict__ b,
                      float* __restrict__ c, int n) {
  int i = blockIdx.x * blockDim.x + threadIdx.x;
  if (i < n) c[i] = a[i] + b[i];
}

// ---------------- enc_out (256 x 500) -> enc_outT (500 x 256) ----------------
__global__ __launch_bounds__(256) void transposeE_k(const float* __restrict__ A,
                                                    float* __restrict__ B) {
  __shared__ float t[64][65];
  int c0 = blockIdx.x * 64;   // col (0..500)
  int r0 = blockIdx.y * 64;   // row (0..256)
  int tx = threadIdx.x & 63, ty = threadIdx.x >> 6;
  #pragma unroll
  for (int i = 0; i < 64; i += 4) {
    int r = r0 + ty + i, c = c0 + tx;
    if (r < SEQ && c < 500) t[ty + i][tx] = A[(size_t)r * 500 + c];
  }
  __syncthreads();
  #pragma unroll
  for (int i = 0; i < 64; i += 4) {
    int c = c0 + ty + i, r = r0 + tx;
    if (c < 500 && r < SEQ) B[(size_t)c * SEQ + r] = t[tx][ty + i];
  }
}

// ---------------- per-unit GRU cell; publishes tagged ----------------
__device__ __forceinline__ void cell_unit_tag(int u, int lane,
    const float* xf, const float* hf,
    const float* __restrict__ Wih, const float* __restrict__ Whh,
    const float* __restrict__ bih, const float* __restrict__ bhh,
    ull* htag, unsigned want) {
  float g[6];
  #pragma unroll
  for (int kind = 0; kind < 6; ++kind) {
    const float* row = (kind < 3) ? (Wih + (size_t)(kind * 500 + u) * 500)
                                  : (Whh + (size_t)((kind - 3) * 500 + u) * 500);
    const float* vec = (kind < 3) ? xf : hf;
    float acc = 0.f;
    #pragma unroll
    for (int j = 0; j < 8; ++j) {
      int k = lane + 64 * j;
      if (k < 500) acc += row[k] * vec[k];
    }
    g[kind] = wred(acc);
  }
  if (lane == 0) {
    float r = sigmoidf_(g[0] + bih[u]        + g[3] + bhh[u]);
    float z = sigmoidf_(g[1] + bih[500 + u]  + g[4] + bhh[500 + u]);
    float n = tanhf(    g[2] + bih[1000 + u] + r * (g[5] + bhh[1000 + u]));
    float hv = (1.f - z) * n + z * hf[u];
    gstore64(&htag[u], ((ull)want << 32) | (ull)__float_as_uint(hv));
  }
}

// ---------------- PERSISTENT decoder: out_W fully on-chip ----------------
// 256 blocks x 512 threads, 1 block/CU (LDS-forced; grid == CU count -> all
// resident). Every block holds 96 rows in VGPRs (12/wave, 24 float4 = 96 regs;
// cap is 256 via launch_bounds(512,1)) + 72 rows in LDS (144 KB) for the whole
// kernel. The remaining 7249 rows (29/block, ~1.8 MB/XCD) stay L2-resident
// after step 0. F-phase is VALU/LDS-bound with ~zero HBM traffic.
__global__ __launch_bounds__(512, 1) void dec_persist(
    const float* __restrict__ emb,
    const float* __restrict__ dWih, const float* __restrict__ dWhh,
    const float* __restrict__ dbih, const float* __restrict__ dbhh,
    const float* __restrict__ enc_out, const float* __restrict__ enc_outT,
    const float* __restrict__ cW, const float* __restrict__ cb,
    const float* __restrict__ outW, const float* __restrict__ outb,
    ull* __restrict__ th0a, ull* __restrict__ th0b,
    ull* __restrict__ th1a, ull* __restrict__ th1b,
    ull* __restrict__ tsc, ull* __restrict__ tctx, ull* __restrict__ tcvec,
    ull* __restrict__ ttok, ull* __restrict__ pmt, ull* __restrict__ psix,
    float* __restrict__ lg0, float* __restrict__ lg1,
    float* __restrict__ stats, float* __restrict__ out_tokens,
    float* __restrict__ out_probs) {
  __shared__ float4 lds_w4[WLR * 125];  // 144000 B of out_W rows
  __shared__ float4 v4[250];            // xf[0..500) + hf[500..1000)
  __shared__ float hfull[512];
  __shared__ float red[256], sc[256];
  __shared__ float wm[8], wsum[8]; __shared__ int wix[8];
  __shared__ float mm[256], ms[256]; __shared__ int mi[256];
  __shared__ int sh_tk;
  float* xf = (float*)v4;
  float* hf = xf + 500;
  int tid = threadIdx.x, lane = tid & 63, wid = tid >> 6, blk = blockIdx.x;
  bool worker = blk < WKB;
  int u = blk * 8 + wid;

  // ---- one-time staging: register rows + LDS rows of out_W ----
  int rbase = blk * NWR + wid * RPW;          // this wave's 12 register rows
  float4 wa[RPW], wb[RPW];
  {
    const float4* w4g = (const float4*)outW;
    #pragma unroll
    for (int rr = 0; rr < RPW; ++rr) {
      size_t ro = (size_t)(rbase + rr) * 125;
      wa[rr] = (lane < 125) ? w4g[ro + lane] : make_float4(0.f, 0.f, 0.f, 0.f);
      wb[rr] = (lane + 64 < 125) ? w4g[ro + lane + 64] : make_float4(0.f, 0.f, 0.f, 0.f);
    }
    float* lw = (float*)lds_w4;
    const float* src = outW + (size_t)(LDS0 + blk * WLR) * 500;
    for (int i = tid; i < WLR * 500; i += 512) lw[i] = src[i];
  }
  int lrow0 = LDS0 + blk * WLR;               // block's first LDS row (global idx)
  int sg0 = STR0 + blk * SPB;                 // block's streamed range
  int sgn = V - sg0; if (sgn > SPB) sgn = SPB; if (sgn < 0) sgn = 0;
  __syncthreads();

  for (int st = 0; st < TDEC; ++st) {
    unsigned want = (unsigned)(st + 1);
    ull* h0r = (st & 1) ? th0b : th0a;
    ull* h0w = (st & 1) ? th0a : th0b;
    ull* h1r = (st & 1) ? th1b : th1a;
    ull* h1w = (st & 1) ? th1a : th1b;
    float* lg_w = (st & 1) ? lg1 : lg0;
    const float* lg_r = (st & 1) ? lg0 : lg1;

    if (worker) {
      // ---- A: layer-0 cell ----
      if (tid == 0) {
        ull tv;
        for (;;) {
          tv = gload64(ttok);
          if ((unsigned)(tv >> 32) == want) break;
          __builtin_amdgcn_s_sleep(1);
        }
        sh_tk = (int)(unsigned)tv;
      }
      __syncthreads();
      int tk = sh_tk;
      if (tid >= 64) {
        for (int i = tid - 64; i < 500; i += 448) xf[i] = emb[(size_t)tk * 500 + i];
      } else {
        #pragma unroll
        for (int j = 0; j < 8; ++j) {
          int k = tid + (j << 6);
          if (k < 500) hf[k] = __uint_as_float((unsigned)gload64(&h0r[k]));  // gated
        }
      }
      __syncthreads();
      if (u < 500) cell_unit_tag(u, lane, xf, hf, dWih, dWhh, dbih, dbhh, h0w, want);
      __syncthreads();

      // ---- B: layer-1 cell ----
      if (tid >= 64) {
        for (int i = tid - 64; i < 500; i += 448)
          hf[i] = __uint_as_float((unsigned)gload64(&h1r[i]));               // gated
      }
      poll_tags<500, 1>(h0w, want, xf, tid);
      if (u < 500) cell_unit_tag(u, lane, xf, hf,
          dWih + 750000, dWhh + 750000, dbih + 1500, dbhh + 1500, h1w, want);
      __syncthreads();

      // ---- C: attention scores (blocks 0..31, 8 each) ----
      if (blk < 32) {
        poll_tags<500, 1>(h1w, want, hfull, tid);
        int s = blk * 8 + wid;
        const float* row = enc_out + (size_t)s * 500;
        float acc = 0.f;
        #pragma unroll
        for (int j = 0; j < 8; ++j) {
          int k = lane + 64 * j;
          if (k < 500) acc += row[k] * hfull[k];
        }
        acc = wred(acc);
        if (lane == 0) gstore64(&tsc[s], ((ull)want << 32) | (ull)__float_as_uint(acc));
        poll_tags<256, 1>(tsc, want, sc, tid);
      } else {
        poll2_tags(h1w, hfull, tsc, sc, want, tid);
      }

      // ---- D: softmax (local) + ctx (8 cols/block, coalesced via enc_outT) ----
      {
        float myv = (tid < 256) ? sc[tid] : 0.f;
        if (tid < 256) red[tid] = myv;
        __syncthreads();
        for (int s = 128; s > 0; s >>= 1) {
          if (tid < s) red[tid] = fmaxf(red[tid], red[tid + s]);
          __syncthreads();
        }
        float m = red[0]; __syncthreads();
        float e = 0.f;
        if (tid < 256) { e = expf(myv - m); red[tid] = e; }
        __syncthreads();
        for (int s = 128; s > 0; s >>= 1) {
          if (tid < s) red[tid] += red[tid + s];
          __syncthreads();
        }
        float inv = 1.f / red[0]; __syncthreads();
        if (tid < 256) sc[tid] = e * inv;
        __syncthreads();
        int j = blk * 8 + wid;
        if (j < 500) {
          const float* col = enc_outT + (size_t)j * SEQ;
          float acc = 0.f;
          #pragma unroll
          for (int q = 0; q < 4; ++q) {
            int s = lane + 64 * q;
            acc += sc[s] * col[s];
          }
          acc = wred(acc);
          if (lane == 0) gstore64(&tctx[j], ((ull)want << 32) | (ull)__float_as_uint(acc));
        }
      }

      // ---- E: cvec (8 rows/block) ----
      if (tid >= 64) for (int i = tid - 64; i < 500; i += 448) xf[i] = hfull[i];
      poll_tags<500, 1>(tctx, want, hf, tid);
      {
        int i = blk * 8 + wid;
        if (i < 500) {
          const float* row = cW + (size_t)i * 1000;
          float acc = 0.f;
          #pragma unroll
          for (int j = 0; j < 16; ++j) {
            int k = lane + 64 * j;
            if (k < 1000) acc += row[k] * xf[k];
          }
          acc = wred(acc);
          if (lane == 0)
            gstore64(&tcvec[i], ((ull)want << 32) | (ull)__float_as_uint(tanhf(acc + cb[i])));
        }
      }
      __syncthreads();
    } else {
      // ---- non-workers: gate on ttok, then write prev-step probs during A..E ----
      if (tid == 0) {
        while ((unsigned)(gload64(ttok) >> 32) < want) __builtin_amdgcn_s_sleep(2);
      }
      __syncthreads();
      if (st > 0) {
        float mM = gload(&stats[2 * (st - 1)]), iS = gload(&stats[2 * (st - 1) + 1]);
        int rg0 = blk * NWR;
        for (int r = tid; r < NWR + WLR + sgn; r += 512) {
          int v = (r < NWR) ? (rg0 + r)
                : (r < NWR + WLR) ? (lrow0 + r - NWR)
                : (sg0 + r - NWR - WLR);
          out_probs[(size_t)(st - 1) * V + v] = expf(lg_r[v] - mM) * iS;
        }
      }
    }

    // ---- F: logits over 3 row groups + per-wave online-softmax partials ----
    if (worker) poll_tags<500, 1>(tcvec, want, xf, tid);
    else        poll_tags<500, 16>(tcvec, want, xf, tid);
    const float4* c4 = v4;
    {
      float m = -1e30f, ssum = 0.f; int ix = V;
      float4 cc0 = (lane < 125) ? c4[lane] : make_float4(0.f, 0.f, 0.f, 0.f);
      float4 cc1 = (lane + 64 < 125) ? c4[lane + 64] : make_float4(0.f, 0.f, 0.f, 0.f);
      // group 1: register rows (ascending, lowest indices)
      #pragma unroll
      for (int rr = 0; rr < RPW; ++rr) {
        float a = 0.f;
        if (lane < 125)
          a += wa[rr].x * cc0.x + wa[rr].y * cc0.y + wa[rr].z * cc0.z + wa[rr].w * cc0.w;
        if (lane + 64 < 125)
          a += wb[rr].x * cc1.x + wb[rr].y * cc1.y + wb[rr].z * cc1.z + wb[rr].w * cc1.w;
        float l = wred(a);
        if (lane == 0) {
          int row = rbase + rr;
          l += outb[row];
          lg_w[row] = l;
          if (l > m) { ssum = ssum * expf(m - l) + 1.f; m = l; ix = row; }
          else       { ssum += expf(l - m); }
        }
      }
      // group 2: LDS rows (9 per wave)
      #pragma unroll
      for (int rr = 0; rr < 9; ++rr) {
        int lrow = wid * 9 + rr;
        float a = 0.f;
        if (lane < 125) {
          float4 w4 = lds_w4[lrow * 125 + lane];
          a += w4.x * cc0.x + w4.y * cc0.y + w4.z * cc0.z + w4.w * cc0.w;
        }
        if (lane + 64 < 125) {
          float4 w4 = lds_w4[lrow * 125 + lane + 64];
          a += w4.x * cc1.x + w4.y * cc1.y + w4.z * cc1.z + w4.w * cc1.w;
        }
        float l = wred(a);
        if (lane == 0) {
          int row = lrow0 + lrow;
          l += outb[row];
          lg_w[row] = l;
          if (l > m) { ssum = ssum * expf(m - l) + 1.f; m = l; ix = row; }
          else       { ssum += expf(l - m); }
        }
      }
      // group 3: streamed rows (L2-resident after step 0)
      {
        int ls = wid * 4, le = ls + 4;
        if (ls > sgn) ls = sgn;
        if (le > sgn) le = sgn;
        for (int r = ls; r < le; ++r) {
          int row = sg0 + r;
          const float4* wrow = (const float4*)(outW + (size_t)row * 500);
          float a = 0.f;
          if (lane < 125) {
            float4 w4 = wrow[lane];
            a += w4.x * cc0.x + w4.y * cc0.y + w4.z * cc0.z + w4.w * cc0.w;
          }
          if (lane + 64 < 125) {
            float4 w4 = wrow[lane + 64];
            a += w4.x * cc1.x + w4.y * cc1.y + w4.z * cc1.z + w4.w * cc1.w;
          }
          float l = wred(a);
          if (lane == 0) {
            l += outb[row];
            lg_w[row] = l;
            if (l > m) { ssum = ssum * expf(m - l) + 1.f; m = l; ix = row; }
            else       { ssum += expf(l - m); }
          }
        }
      }
      if (lane == 0) { wm[wid] = m; wsum[wid] = ssum; wix[wid] = ix; }
    }
    __syncthreads();
    if (tid == 0) {
      float M = wm[0], S = wsum[0]; int I = wix[0];
      for (int w2 = 1; w2 < 8; ++w2) {
        if (wm[w2] > M) { S = S * expf(M - wm[w2]) + wsum[w2]; M = wm[w2]; I = wix[w2]; }
        else            { S += wsum[w2] * expf(wm[w2] - M); }
      }
      // publish {s, ix} first, then tagged {tag, m} (waitcnt-ordered)
      gstore64(&psix[blk], ((ull)__float_as_uint(S) << 32) | (ull)(unsigned)I);
      __builtin_amdgcn_s_waitcnt(0);
      gstore64(&pmt[blk], ((ull)want << 32) | (ull)__float_as_uint(M));
    }
    __syncthreads();

    // ---- block 0: parallel-poll all 256 tagged partials, merge, publish ----
    if (blk == 0) {
      if (tid < 256) {
        ull tv;
        while ((unsigned)((tv = gload64(&pmt[tid])) >> 32) != want)
          __builtin_amdgcn_s_sleep(2);
        mm[tid] = __uint_as_float((unsigned)tv);
        ull sv = gload64(&psix[tid]);
        ms[tid] = __uint_as_float((unsigned)(sv >> 32));
        mi[tid] = (int)(unsigned)sv;
      }
      __syncthreads();
      for (int s = 128; s > 0; s >>= 1) {
        if (tid < s) {
          float ma = mm[tid], mb = mm[tid + s];
          float sa = ms[tid], sb = ms[tid + s];
          int ia = mi[tid], ib = mi[tid + s];
          if (mb > ma || (mb == ma && ib < ia)) {
            ms[tid] = sa * expf(ma - mb) + sb; mm[tid] = mb; mi[tid] = ib;
          } else {
            ms[tid] = sa + sb * expf(mb - ma);
          }
        }
        __syncthreads();
      }
      if (tid == 0) {
        out_tokens[st] = (float)mi[0];
        gstore(&stats[2 * st], mm[0]);
        gstore(&stats[2 * st + 1], 1.f / ms[0]);
        __builtin_amdgcn_s_waitcnt(0);     // stats at LLC before tok publish
        gstore64(ttok, ((ull)(unsigned)(st + 2) << 32) | (ull)(unsigned)mi[0]);
      }
      __syncthreads();
    }

    // ---- workers: prev-step probs at end of step (their 3 row groups) ----
    if (worker && st > 0) {
      float mM = gload(&stats[2 * (st - 1)]), iS = gload(&stats[2 * (st - 1) + 1]);
      int rg0 = blk * NWR;
      for (int r = tid; r < NWR + WLR + sgn; r += 512) {
        int v = (r < NWR) ? (rg0 + r)
              : (r < NWR + WLR) ? (lrow0 + r - NWR)
              : (sg0 + r - NWR - WLR);
        out_probs[(size_t)(st - 1) * V + v] = expf(lg_r[v] - mM) * iS;
      }
    }
    __syncthreads();
  }
}

// ---------------- wide probs write for the final step ----------------
__global__ __launch_bounds__(256) void probs_k(const float* __restrict__ logits,
    const float* __restrict__ stats, float* __restrict__ out_probs) {
  int v = blockIdx.x * 256 + threadIdx.x;
  if (v < V) out_probs[v] = expf(logits[v] - stats[0]) * stats[1];
}

extern "C" void kernel_launch(void* const* d_in, const int* in_sizes, int n_in,
                              void* d_out, int out_size, void* d_ws, size_t ws_size,
                              hipStream_t stream) {
  const int*   seq   = (const int*)d_in[0];
  const float* emb   = (const float*)d_in[3];
  const float* e0f_Wih = (const float*)d_in[4];
  const float* e0f_Whh = (const float*)d_in[5];
  const float* e0f_bih = (const float*)d_in[6];
  const float* e0f_bhh = (const float*)d_in[7];
  const float* e0b_Wih = (const float*)d_in[8];
  const float* e0b_Whh = (const float*)d_in[9];
  const float* e0b_bih = (const float*)d_in[10];
  const float* e0b_bhh = (const float*)d_in[11];
  const float* e1f_Wih = (const float*)d_in[12];
  const float* e1f_Whh = (const float*)d_in[13];
  const float* e1f_bih = (const float*)d_in[14];
  const float* e1f_bhh = (const float*)d_in[15];
  const float* e1b_Wih = (const float*)d_in[16];
  const float* e1b_Whh = (const float*)d_in[17];
  const float* e1b_bih = (const float*)d_in[18];
  const float* e1b_bhh = (const float*)d_in[19];
  const float* dWih = (const float*)d_in[20];
  const float* dWhh = (const float*)d_in[21];
  const float* dbih = (const float*)d_in[22];
  const float* dbhh = (const float*)d_in[23];
  const float* cW   = (const float*)d_in[24];
  const float* cb   = (const float*)d_in[25];
  const float* outW = (const float*)d_in[26];
  const float* outb = (const float*)d_in[27];

  float* w = (float*)d_ws;
  float* ex      = w;                      // 128000
  float* x1      = ex + 128000;            // 256000
  float* gxf     = x1 + 256000;            // 384000
  float* gxb     = gxf + 384000;           // 384000
  float* y1f     = gxb + 384000;           // 128000
  float* y1b     = y1f + 128000;           // 128000
  float* enc_out = y1b + 128000;           // 128000
  float* lg0     = enc_out + 128000;       // 50432
  float* lg1     = lg0 + 50432;            // 50432
  float* stats   = lg1 + 50432;            // 192 (2 per step)
  ull*   htag    = (ull*)(stats + 192);    // scan tags: 4096 ull (8B-aligned)
  ull* tL0F_A = htag;        ull* tL0F_B = htag + 512;
  ull* tL0B_A = htag + 1024; ull* tL0B_B = htag + 1536;
  ull* tL1F_A = htag + 2048; ull* tL1F_B = htag + 2560;
  ull* tL1B_A = htag + 3072; ull* tL1B_B = htag + 3584;
  ull*   dtag    = htag + 4096;            // decoder tags: 4416 ull
  ull* th0a  = dtag;        ull* th0b = dtag + 512;
  ull* th1a  = dtag + 1024; ull* th1b = dtag + 1536;
  ull* tsc   = dtag + 2048; ull* tctx = dtag + 2304;
  ull* tcvec = dtag + 2816; ull* ttok = dtag + 3328;
  ull* pmt   = dtag + 3392; ull* psix = dtag + 3904;
  float* enc_outT = (float*)(dtag + 4416); // 128000 floats (500 x 256)

  float* outf = (float*)d_out;

  // zero all tag buffers (d_ws is re-poisoned before every call)
  (void)hipMemsetAsync(htag, 0, (4096 + 4416) * sizeof(ull), stream);

  init_k<<<1, 64, 0, stream>>>(ttok);
  embed_k<<<SEQ, 128, 0, stream>>>(seq, emb, ex);

  // encoder layer 0
  gemm_nt<<<dim3(24, 4), 256, 0, stream>>>(ex, e0f_Wih, e0f_bih, gxf, SEQ, H3, H);
  gemm_nt<<<dim3(24, 4), 256, 0, stream>>>(ex, e0b_Wih, e0b_bih, gxb, SEQ, H3, H);
  gru_scan_tag<<<2 * SB, 512, 0, stream>>>(gxf, gxb, e0f_Whh, e0b_Whh,
      e0f_bhh, e0b_bhh, tL0F_A, tL0F_B, tL0B_A, tL0B_B, x1, x1 + 500, 1000);

  // encoder layer 1
  gemm_nt<<<dim3(24, 4), 256, 0, stream>>>(x1, e1f_Wih, e1f_bih, gxf, SEQ, H3, 2 * H);
  gemm_nt<<<dim3(24, 4), 256, 0, stream>>>(x1, e1b_Wih, e1b_bih, gxb, SEQ, H3, 2 * H);
  gru_scan_tag<<<2 * SB, 512, 0, stream>>>(gxf, gxb, e1f_Whh, e1b_Whh,
      e1f_bhh, e1b_bhh, tL1F_A, tL1F_B, tL1B_A, tL1B_B, y1f, y1b, 500);
  add_k<<<(SEQ * H + 255) / 256, 256, 0, stream>>>(y1f, y1b, enc_out, SEQ * H);
  transposeE_k<<<dim3(8, 4), 256, 0, stream>>>(enc_out, enc_outT);

  // seed decoder h tags (layer-0 final states live in the A buffers)
  seed_k<<<1, 512, 0, stream>>>(tL0F_A, tL0B_A, th0a, th1a);

  // persistent decoder: ONE launch, 256 blocks (1/CU), out_W fully on-chip
  dec_persist<<<NDB, 512, 0, stream>>>(emb,
      dWih, dWhh, dbih, dbhh, enc_out, enc_outT, cW, cb, outW, outb,
      th0a, th0b, th1a, th1b, tsc, tctx, tcvec, ttok, pmt, psix,
      lg0, lg1, stats, outf, outf + TDEC);

  probs_k<<<NLT, 256, 0, stream>>>(((TDEC - 1) & 1) ? lg1 : lg0,
      stats + 2 * (TDEC - 1), outf + TDEC + (size_t)(TDEC - 1) * V);
}